// Round 1
// baseline (269.165 us; speedup 1.0000x reference)
//
#include <hip/hip_runtime.h>
#include <hip/hip_fp16.h>

#define ND 100000   // N_NODES
#define NE 50000    // N_EDGES
#define AR 32       // EDGE_ARITY
#define DG 16       // NODE_DEG
#define D  128      // D_IN == D_OUT == TV

// ---------------------------------------------------------------------------
// K0: inter_nw = mean(cos(weight3 rows, weight3[0]))  -> single float in ws
// ---------------------------------------------------------------------------
__global__ __launch_bounds__(128) void k_inter(const float* __restrict__ w3,
                                               float* __restrict__ inter_out) {
    int j = threadIdx.x;           // row index 0..127
    float dot = 0.f, sq = 0.f, sq0 = 0.f;
    #pragma unroll 8
    for (int k = 0; k < D; ++k) {
        float wj = w3[j * D + k];
        float w0 = w3[k];          // row 0 == tv
        dot += wj * w0;
        sq  += wj * wj;
        sq0 += w0 * w0;
    }
    float cosj = dot / (sqrtf(sq0) * sqrtf(sq));
    __shared__ float red[128];
    red[j] = cosj;
    __syncthreads();
    if (j == 0) {
        float s = 0.f;
        for (int i = 0; i < 128; ++i) s += red[i];
        inter_out[0] = s / 128.f;
    }
}

// ---------------------------------------------------------------------------
// K1: xw = (x @ w1) * inter_nw, stored as fp16 table (into d_out scratch).
// 32 rows per block, 256 threads, 4x4 register tile per thread.
// LDS: w1 in fp16 (32 KB) + x tile f32 (16 KB) = 48 KB.
// ---------------------------------------------------------------------------
__global__ __launch_bounds__(256) void k_xw(const float* __restrict__ x,
                                            const float* __restrict__ w1,
                                            const float* __restrict__ inter_p,
                                            __half* __restrict__ xwh) {
    __shared__ __half w1h[D * D];   // [k][c], 32 KB
    __shared__ float  xs[32 * D];   // [r][k], 16 KB
    int t = threadIdx.x;

    // load w1 -> fp16 LDS (float4 loads, half2 stores)
    const float4* w1v4 = (const float4*)w1;
    #pragma unroll
    for (int i = 0; i < 16; ++i) {
        float4 v = w1v4[i * 256 + t];
        __half2* dh = (__half2*)&w1h[(i * 256 + t) * 4];
        dh[0] = __floats2half2_rn(v.x, v.y);
        dh[1] = __floats2half2_rn(v.z, v.w);
    }
    // load x tile (32 rows x 128) f32
    int rowbase = blockIdx.x * 32;
    const float4* xg = (const float4*)(x + (size_t)rowbase * D);
    float4* xs4 = (float4*)xs;
    #pragma unroll
    for (int i = 0; i < 4; ++i) xs4[i * 256 + t] = xg[i * 256 + t];
    __syncthreads();

    float inter = inter_p[0];
    int rg = t >> 5;        // 0..7  -> rows rg*4 .. rg*4+3
    int cg = t & 31;        // 0..31 -> cols cg*4 .. cg*4+3
    int r0 = rg * 4;
    int c0 = cg * 4;

    float acc[4][4] = {};
    #pragma unroll 4
    for (int k = 0; k < D; ++k) {
        float xv[4];
        #pragma unroll
        for (int i = 0; i < 4; ++i) xv[i] = xs[(r0 + i) * D + k];
        __half2 wa = *(const __half2*)&w1h[k * D + c0];
        __half2 wb = *(const __half2*)&w1h[k * D + c0 + 2];
        float wc0 = __low2float(wa), wc1 = __high2float(wa);
        float wc2 = __low2float(wb), wc3 = __high2float(wb);
        #pragma unroll
        for (int i = 0; i < 4; ++i) {
            acc[i][0] = fmaf(xv[i], wc0, acc[i][0]);
            acc[i][1] = fmaf(xv[i], wc1, acc[i][1]);
            acc[i][2] = fmaf(xv[i], wc2, acc[i][2]);
            acc[i][3] = fmaf(xv[i], wc3, acc[i][3]);
        }
    }
    #pragma unroll
    for (int i = 0; i < 4; ++i) {
        size_t r = (size_t)(rowbase + r0 + i);
        __half2* dst = (__half2*)(xwh + r * D + c0);
        dst[0] = __floats2half2_rn(acc[i][0] * inter, acc[i][1] * inter);
        dst[1] = __floats2half2_rn(acc[i][2] * inter, acc[i][3] * inter);
    }
}

// ---------------------------------------------------------------------------
// K2: per edge e: edge = relu(sum_a w_a * xw[seq[e,a]]);  e1 = edge @ w2 (fp16 out)
// 256 threads = 4 waves; each half-wave owns one edge (2 edges/wave, 8/block).
// LDS: w2 fp16 (32 KB) + edge buffers (4 KB) = 36 KB.
// ---------------------------------------------------------------------------
__global__ __launch_bounds__(256) void k_edge(const int* __restrict__ seq,
                                              const __half* __restrict__ xwh,
                                              const float* __restrict__ w2,
                                              __half* __restrict__ e1h) {
    __shared__ __half w2h[D * D];   // [c][c'], 32 KB
    __shared__ float  ebuf[8][D];   // per half-wave edge vector
    int t = threadIdx.x;

    const float4* w2v4 = (const float4*)w2;
    #pragma unroll
    for (int i = 0; i < 16; ++i) {
        float4 v = w2v4[i * 256 + t];
        __half2* dh = (__half2*)&w2h[(i * 256 + t) * 4];
        dh[0] = __floats2half2_rn(v.x, v.y);
        dh[1] = __floats2half2_rn(v.z, v.w);
    }

    int wave = t >> 6;
    int lane = t & 63;
    int sub  = lane >> 5;     // which edge of this wave's pair
    int il   = lane & 31;     // arity slot
    int gw   = blockIdx.x * 4 + wave;
    int e    = gw * 2 + sub;  // edge id, always < NE (6250*4*2 == 50000)

    int  sval  = seq[(size_t)e * AR + il];
    bool valid = sval > 0;
    unsigned long long b = __ballot(valid);
    int cnt = __popcll(sub ? (b >> 32) : (b & 0xffffffffULL));
    const float wuni = 1.f / 32.f;
    float wv = (cnt > 0) ? 1.f / (float)cnt : wuni;

    int c0 = il * 4;
    float a0 = 0.f, a1 = 0.f, a2 = 0.f, a3 = 0.f;
    #pragma unroll
    for (int a = 0; a < AR; ++a) {
        int srow = __shfl(sval, (sub << 5) + a, 64);
        float wa = (cnt > 0) ? ((srow > 0) ? wv : 0.f) : wuni;
        const __half2* p = (const __half2*)(xwh + (size_t)srow * D + c0);
        __half2 v01 = p[0], v23 = p[1];
        a0 = fmaf(wa, __low2float(v01),  a0);
        a1 = fmaf(wa, __high2float(v01), a1);
        a2 = fmaf(wa, __low2float(v23),  a2);
        a3 = fmaf(wa, __high2float(v23), a3);
    }
    float* eb = ebuf[wave * 2 + sub];
    eb[c0 + 0] = fmaxf(a0, 0.f);
    eb[c0 + 1] = fmaxf(a1, 0.f);
    eb[c0 + 2] = fmaxf(a2, 0.f);
    eb[c0 + 3] = fmaxf(a3, 0.f);
    __syncthreads();   // w2h ready + edge vectors ready

    float o0 = 0.f, o1 = 0.f, o2 = 0.f, o3 = 0.f;
    #pragma unroll 4
    for (int c = 0; c < D; ++c) {
        float ec = eb[c];
        __half2 wa2 = *(const __half2*)&w2h[c * D + c0];
        __half2 wb2 = *(const __half2*)&w2h[c * D + c0 + 2];
        o0 = fmaf(ec, __low2float(wa2),  o0);
        o1 = fmaf(ec, __high2float(wa2), o1);
        o2 = fmaf(ec, __low2float(wb2),  o2);
        o3 = fmaf(ec, __high2float(wb2), o3);
    }
    __half2* dst = (__half2*)(e1h + (size_t)e * D + c0);
    dst[0] = __floats2half2_rn(o0, o1);
    dst[1] = __floats2half2_rn(o2, o3);
}

// ---------------------------------------------------------------------------
// K3: node[n] = sum_k u_w * e1[useq[n,k]]  -> f32 output
// one wave per node, 4 nodes per 256-thread block.
// ---------------------------------------------------------------------------
__global__ __launch_bounds__(256) void k_node(const int* __restrict__ useq,
                                              const __half* __restrict__ e1h,
                                              float* __restrict__ out) {
    int t = threadIdx.x;
    int wave = t >> 6, lane = t & 63;
    int n = blockIdx.x * 4 + wave;    // always < ND (25000*4 == 100000)

    int  sval  = useq[(size_t)n * DG + (lane & 15)];
    bool valid = sval > 0;
    unsigned long long b = __ballot(valid);
    int cnt = __popcll(b & 0xFFFFULL);
    const float wuni = 1.f / 16.f;
    float wv = (cnt > 0) ? 1.f / (float)cnt : wuni;

    float a0 = 0.f, a1 = 0.f;
    #pragma unroll
    for (int k = 0; k < DG; ++k) {
        int srow = __shfl(sval, k, 64);
        float wa = (cnt > 0) ? ((srow > 0) ? wv : 0.f) : wuni;
        __half2 v = *(const __half2*)(e1h + (size_t)srow * D + lane * 2);
        a0 = fmaf(wa, __low2float(v),  a0);
        a1 = fmaf(wa, __high2float(v), a1);
    }
    float2* dst = (float2*)(out + (size_t)n * D + lane * 2);
    *dst = make_float2(a0, a1);
}

// ---------------------------------------------------------------------------
extern "C" void kernel_launch(void* const* d_in, const int* in_sizes, int n_in,
                              void* d_out, int out_size, void* d_ws, size_t ws_size,
                              hipStream_t stream) {
    const float* x    = (const float*)d_in[0];
    const int*   seq  = (const int*)d_in[1];
    const int*   useq = (const int*)d_in[2];
    // d_in[3] = TextVector: unused (reference overwrites it with weight3[0])
    const float* w1   = (const float*)d_in[4];
    const float* w2   = (const float*)d_in[5];
    const float* w3   = (const float*)d_in[6];
    float* out = (float*)d_out;

    // Scratch layout:
    //   xw fp16 table (25.6 MB) lives in d_out (51.2 MB) — fully overwritten by k_node.
    //   d_ws: [0]=inter_nw scalar, [256 ..] = e1 fp16 table (12.8 MB).
    __half* xwh   = (__half*)d_out;
    float*  inter = (float*)d_ws;
    __half* e1h   = (__half*)((char*)d_ws + 256);

    hipLaunchKernelGGL(k_inter, dim3(1),       dim3(128), 0, stream, w3, inter);
    hipLaunchKernelGGL(k_xw,    dim3(ND / 32), dim3(256), 0, stream, x, w1, inter, xwh);
    hipLaunchKernelGGL(k_edge,  dim3(NE / 8),  dim3(256), 0, stream, seq, xwh, w2, e1h);
    hipLaunchKernelGGL(k_node,  dim3(ND / 4),  dim3(256), 0, stream, useq, e1h, out);
}

// Round 2
// 230.345 us; speedup vs baseline: 1.1685x; 1.1685x over previous
//
#include <hip/hip_runtime.h>
#include <hip/hip_fp16.h>

#define ND 100000   // N_NODES
#define NE 50000    // N_EDGES
#define AR 32       // EDGE_ARITY
#define DG 16       // NODE_DEG
#define D  128      // D_IN == D_OUT == TV

typedef _Float16 half8_t __attribute__((ext_vector_type(8)));
typedef _Float16 half4_t __attribute__((ext_vector_type(4)));
typedef float    f32x4_t __attribute__((ext_vector_type(4)));

// A-row stride in LDS (halves): 128 + 8 pad -> 272 B row stride, keeps 16 B
// alignment for half8 loads and only 2-way (free) bank aliasing on A-frag reads.
#define APAD 136

// ---------------------------------------------------------------------------
// K0: inter_nw = mean(cos(weight3 rows, weight3[0]))  -> single float in ws
// ---------------------------------------------------------------------------
__global__ __launch_bounds__(128) void k_inter(const float* __restrict__ w3,
                                               float* __restrict__ inter_out) {
    int j = threadIdx.x;           // row index 0..127
    float dot = 0.f, sq = 0.f, sq0 = 0.f;
    #pragma unroll 8
    for (int k = 0; k < D; ++k) {
        float wj = w3[j * D + k];
        float w0 = w3[k];          // row 0 == tv
        dot += wj * w0;
        sq  += wj * wj;
        sq0 += w0 * w0;
    }
    float cosj = dot / (sqrtf(sq0) * sqrtf(sq));
    __shared__ float red[128];
    red[j] = cosj;
    __syncthreads();
    if (j == 0) {
        float s = 0.f;
        for (int i = 0; i < 128; ++i) s += red[i];
        inter_out[0] = s / 128.f;
    }
}

// ---------------------------------------------------------------------------
// K0b: convert w1,w2 (f32 row-major [k][n]) to fragment-major fp16 in ws.
// Fragment-major index: o = ((ntile*4 + ktile)*64 + lane)*8 + j
//   <-> element B[k = ktile*32 + (lane>>4)*8 + j][n = ntile*16 + (lane&15)]
// so each MFMA b-frag is one contiguous 1 KB run (lane-contiguous 16 B).
// ---------------------------------------------------------------------------
__global__ __launch_bounds__(256) void k_prep(const float* __restrict__ w1,
                                              const float* __restrict__ w2,
                                              _Float16* __restrict__ w1f,
                                              _Float16* __restrict__ w2f) {
    int o = blockIdx.x * 256 + threadIdx.x;   // 0..16383
    int j    = o & 7;
    int lane = (o >> 3) & 63;
    int frag = o >> 9;                        // 0..31
    int ntile = frag >> 2, ktile = frag & 3;
    int n = ntile * 16 + (lane & 15);
    int k = ktile * 32 + (lane >> 4) * 8 + j;
    w1f[o] = (_Float16)w1[k * D + n];
    w2f[o] = (_Float16)w2[k * D + n];
}

// ---------------------------------------------------------------------------
// K1: xw = (x @ w1) * inter_nw via MFMA fp16 -> fp16 table in d_out scratch.
// 64 rows/block, 256 threads = 4 waves; wave w computes rows [w*16, w*16+16).
// ---------------------------------------------------------------------------
__global__ __launch_bounds__(256) void k_xw(const float* __restrict__ x,
                                            const _Float16* __restrict__ w1f_g,
                                            const float* __restrict__ inter_p,
                                            _Float16* __restrict__ xwh) {
    __shared__ _Float16 wfrag[D * D];     // 32 KB, fragment-major
    __shared__ _Float16 xs[64 * APAD];    // 17 KB, row-major A tile (fp16)
    int t = threadIdx.x;

    // stage w1 fragments: plain 16 B copies
    {
        const float4* src = (const float4*)w1f_g;
        float4* dst = (float4*)wfrag;
        #pragma unroll
        for (int i = 0; i < 8; ++i) dst[i * 256 + t] = src[i * 256 + t];
    }
    // stage x tile (64 rows), convert f32 -> fp16, zero-fill OOB rows
    int rowbase = blockIdx.x * 64;
    #pragma unroll
    for (int p = 0; p < 8; ++p) {
        int idx = p * 1024 + t * 4;          // float index within tile
        int r = idx >> 7, c = idx & 127;
        int grow = rowbase + r;
        float4 v = make_float4(0.f, 0.f, 0.f, 0.f);
        if (grow < ND) v = ((const float4*)x)[(size_t)grow * 32 + (c >> 2)];
        half4_t h = { (_Float16)v.x, (_Float16)v.y, (_Float16)v.z, (_Float16)v.w };
        *(half4_t*)&xs[r * APAD + c] = h;
    }
    __syncthreads();

    int wave = t >> 6, lane = t & 63;
    int quad = lane >> 4, l15 = lane & 15;
    int m0 = wave * 16;
    float inter = inter_p[0];

    half8_t a[4];
    #pragma unroll
    for (int kt = 0; kt < 4; ++kt)
        a[kt] = *(const half8_t*)&xs[(m0 + l15) * APAD + kt * 32 + quad * 8];

    #pragma unroll
    for (int nt = 0; nt < 8; ++nt) {
        f32x4_t acc = {0.f, 0.f, 0.f, 0.f};
        #pragma unroll
        for (int kt = 0; kt < 4; ++kt) {
            half8_t b = *(const half8_t*)&wfrag[((nt * 4 + kt) * 64 + lane) * 8];
            acc = __builtin_amdgcn_mfma_f32_16x16x32_f16(a[kt], b, acc, 0, 0, 0);
        }
        int col = nt * 16 + l15;
        #pragma unroll
        for (int i = 0; i < 4; ++i) {
            int grow = rowbase + m0 + quad * 4 + i;
            if (grow < ND)
                xwh[(size_t)grow * D + col] = (_Float16)(acc[i] * inter);
        }
    }
}

// ---------------------------------------------------------------------------
// K2: gather 32 edges/block -> relu'd fp16 A-tile in LDS -> MFMA @w2 -> e1h.
// Gather: each half-wave owns one edge (8 edges per pass, 4 passes).
// MFMA: wave w -> mtile w>>1, ntiles (w&1)*4 .. +3.
// ---------------------------------------------------------------------------
__global__ __launch_bounds__(256) void k_edge(const int* __restrict__ seq,
                                              const _Float16* __restrict__ xwh,
                                              const _Float16* __restrict__ w2f_g,
                                              _Float16* __restrict__ e1h) {
    __shared__ _Float16 wfrag[D * D];     // 32 KB
    __shared__ _Float16 et[32 * APAD];    // 8.7 KB edge A-tile
    int t = threadIdx.x;
    {
        const float4* src = (const float4*)w2f_g;
        float4* dst = (float4*)wfrag;
        #pragma unroll
        for (int i = 0; i < 8; ++i) dst[i * 256 + t] = src[i * 256 + t];
    }

    int wave = t >> 6, lane = t & 63;
    int sub = lane >> 5, il = lane & 31;
    int eb0 = blockIdx.x * 32;

    #pragma unroll
    for (int p = 0; p < 4; ++p) {
        int erow = p * 8 + wave * 2 + sub;       // 0..31
        int e = eb0 + erow;
        int es = (e < NE) ? e : (NE - 1);
        int sval = seq[(size_t)es * AR + il];
        unsigned long long b = __ballot(sval > 0);
        int cnt = __popcll(sub ? (unsigned long long)(b >> 32)
                               : (b & 0xffffffffULL));
        const float wuni = 1.f / 32.f;
        float wv = (cnt > 0) ? 1.f / (float)cnt : wuni;
        int c0 = il * 4;
        float a0 = 0.f, a1 = 0.f, a2 = 0.f, a3 = 0.f;
        #pragma unroll
        for (int a = 0; a < AR; ++a) {
            int srow = __shfl(sval, (sub << 5) + a, 64);
            float wa = (cnt > 0) ? ((srow > 0) ? wv : 0.f) : wuni;
            half4_t v = *(const half4_t*)(xwh + (size_t)srow * D + c0);
            a0 = fmaf(wa, (float)v[0], a0);
            a1 = fmaf(wa, (float)v[1], a1);
            a2 = fmaf(wa, (float)v[2], a2);
            a3 = fmaf(wa, (float)v[3], a3);
        }
        half4_t h = { (_Float16)fmaxf(a0, 0.f), (_Float16)fmaxf(a1, 0.f),
                      (_Float16)fmaxf(a2, 0.f), (_Float16)fmaxf(a3, 0.f) };
        *(half4_t*)&et[erow * APAD + c0] = h;
    }
    __syncthreads();

    int quad = lane >> 4, l15 = lane & 15;
    int m0 = (wave >> 1) * 16;
    int ng = (wave & 1) * 4;

    half8_t a[4];
    #pragma unroll
    for (int kt = 0; kt < 4; ++kt)
        a[kt] = *(const half8_t*)&et[(m0 + l15) * APAD + kt * 32 + quad * 8];

    #pragma unroll
    for (int nt2 = 0; nt2 < 4; ++nt2) {
        int nt = ng + nt2;
        f32x4_t acc = {0.f, 0.f, 0.f, 0.f};
        #pragma unroll
        for (int kt = 0; kt < 4; ++kt) {
            half8_t b = *(const half8_t*)&wfrag[((nt * 4 + kt) * 64 + lane) * 8];
            acc = __builtin_amdgcn_mfma_f32_16x16x32_f16(a[kt], b, acc, 0, 0, 0);
        }
        int col = nt * 16 + l15;
        #pragma unroll
        for (int i = 0; i < 4; ++i) {
            int e = eb0 + m0 + quad * 4 + i;
            if (e < NE)
                e1h[(size_t)e * D + col] = (_Float16)acc[i];
        }
    }
}

// ---------------------------------------------------------------------------
// K3: node[n] = sum_k u_w * e1[useq[n,k]] -> f32 out.
// One wave/node; each half-wave handles one k per iter (2 k's/iter/wave),
// 8 B (half4) per lane.
// ---------------------------------------------------------------------------
__global__ __launch_bounds__(256) void k_node(const int* __restrict__ useq,
                                              const _Float16* __restrict__ e1h,
                                              float* __restrict__ out) {
    int t = threadIdx.x;
    int wave = t >> 6, lane = t & 63;
    int n = blockIdx.x * 4 + wave;    // always < ND (25000*4 == 100000)
    int hf = lane >> 5, il = lane & 31;

    int sval = useq[(size_t)n * DG + (lane & 15)];
    unsigned long long b = __ballot(sval > 0);
    int cnt = __popcll(b & 0xFFFFULL);
    const float wuni = 1.f / 16.f;
    float wv = (cnt > 0) ? 1.f / (float)cnt : wuni;

    float a0 = 0.f, a1 = 0.f, a2 = 0.f, a3 = 0.f;
    #pragma unroll
    for (int i = 0; i < 8; ++i) {
        int k = i * 2 + hf;
        int srow = __shfl(sval, k, 64);
        float wa = (cnt > 0) ? ((srow > 0) ? wv : 0.f) : wuni;
        half4_t v = *(const half4_t*)(e1h + (size_t)srow * D + il * 4);
        a0 = fmaf(wa, (float)v[0], a0);
        a1 = fmaf(wa, (float)v[1], a1);
        a2 = fmaf(wa, (float)v[2], a2);
        a3 = fmaf(wa, (float)v[3], a3);
    }
    // fold upper half-wave into lower, then lanes 0..31 write float4
    a0 += __shfl_down(a0, 32, 64);
    a1 += __shfl_down(a1, 32, 64);
    a2 += __shfl_down(a2, 32, 64);
    a3 += __shfl_down(a3, 32, 64);
    if (lane < 32) {
        float4 o = make_float4(a0, a1, a2, a3);
        ((float4*)(out + (size_t)n * D))[il] = o;
    }
}

// ---------------------------------------------------------------------------
extern "C" void kernel_launch(void* const* d_in, const int* in_sizes, int n_in,
                              void* d_out, int out_size, void* d_ws, size_t ws_size,
                              hipStream_t stream) {
    const float* x    = (const float*)d_in[0];
    const int*   seq  = (const int*)d_in[1];
    const int*   useq = (const int*)d_in[2];
    // d_in[3] = TextVector: unused (reference overwrites it with weight3[0])
    const float* w1   = (const float*)d_in[4];
    const float* w2   = (const float*)d_in[5];
    const float* w3   = (const float*)d_in[6];
    float* out = (float*)d_out;

    // Scratch layout:
    //   xw fp16 table (25.6 MB) in d_out (51.2 MB) — overwritten by k_node.
    //   d_ws: [0] inter scalar | +256 w1frag (32 KB) | +32 KB w2frag | e1h (12.8 MB)
    _Float16* xwh   = (_Float16*)d_out;
    float*    inter = (float*)d_ws;
    _Float16* w1f   = (_Float16*)((char*)d_ws + 256);
    _Float16* w2f   = (_Float16*)((char*)d_ws + 256 + 32768);
    _Float16* e1h   = (_Float16*)((char*)d_ws + 256 + 65536);

    hipLaunchKernelGGL(k_inter, dim3(1),              dim3(128), 0, stream, w3, inter);
    hipLaunchKernelGGL(k_prep,  dim3(64),             dim3(256), 0, stream, w1, w2, w1f, w2f);
    hipLaunchKernelGGL(k_xw,    dim3((ND + 63) / 64), dim3(256), 0, stream, x, w1f, inter, xwh);
    hipLaunchKernelGGL(k_edge,  dim3((NE + 31) / 32), dim3(256), 0, stream, seq, xwh, w2f, e1h);
    hipLaunchKernelGGL(k_node,  dim3(ND / 4),         dim3(256), 0, stream, useq, e1h, out);
}